// Round 7
// baseline (7670.010 us; speedup 1.0000x reference)
//
#include <hip/hip_runtime.h>
#include <stdint.h>

#define N_PTS 65536
#define DIMS 6
#define NSAMP 2048
#define NGRP 64
#define EMB 512
#define ROWS (NSAMP*NGRP)
#define EPS_BN 1e-5f

#define FIRST_MODE 0

// ---------------- Threefry-2x32, 20 rounds (JAX-compatible) ----------------
__device__ __forceinline__ void tf2x32(unsigned k0, unsigned k1, unsigned &x0, unsigned &x1) {
  unsigned ks[3] = {k0, k1, k0 ^ k1 ^ 0x1BD11BDAu};
  const unsigned R[8] = {13,15,26,6,17,29,16,24};
  x0 += ks[0]; x1 += ks[1];
#pragma unroll
  for (int g = 0; g < 5; ++g) {
#pragma unroll
    for (int j = 0; j < 4; ++j) {
      unsigned r = R[(g & 1) * 4 + j];
      x0 += x1;
      x1 = (x1 << r) | (x1 >> (32 - r));
      x1 ^= x0;
    }
    x0 += ks[(g + 1) % 3];
    x1 += ks[(g + 2) % 3] + (unsigned)(g + 1);
  }
}

__device__ __forceinline__ int compute_first(unsigned seed) {
  unsigned k0 = 0u, k1 = seed;
  unsigned s0, s1;
#if (FIRST_MODE == 0) || (FIRST_MODE == 1)
  { unsigned a0 = 0u, a1 = 1u; tf2x32(k0, k1, a0, a1); s0 = a0; s1 = a1; }
#else
  { unsigned p0 = 0u, p1 = 2u; tf2x32(k0, k1, p0, p1);
    unsigned q0 = 1u, q1 = 3u; tf2x32(k0, k1, q0, q1);
    s0 = p1; s1 = q1; }
#endif
  unsigned b0 = 0u, b1v = 0u; tf2x32(s0, s1, b0, b1v);
#if (FIRST_MODE == 0) || (FIRST_MODE == 3)
  unsigned bits = b0 ^ b1v;
#else
  unsigned bits = b0;
#endif
  return (int)(bits & 0xFFFFu);
}

// ---------------- geometry ---------------------------------------------------
#define FPSB 32                      // FPS blocks (32 slots = four 64B lines/iter)
#define MEGA_BLOCKS 256              // 32 FPS + 224 workers; all co-resident
#define FPS_PPT 2                    // 65536 / (32*1024)
#define GB_CAND 512

// ---------------- init -------------------------------------------------------
__global__ __launch_bounds__(256) void k_init(const float* __restrict__ pts,
    const int* __restrict__ seed_arr, unsigned long long* __restrict__ slot,
    float* __restrict__ stats, float4* __restrict__ xyzw,
    int* __restrict__ sampled) {
  int tid = blockIdx.x * 256 + threadIdx.x;        // 65536 threads
  if (tid < N_PTS) {
    float x = pts[tid*6], y = pts[tid*6+1], z = pts[tid*6+2];
    float p2 = __fadd_rn(__fadd_rn(__fmul_rn(x,x), __fmul_rn(y,y)), __fmul_rn(z,z));
    xyzw[tid] = make_float4(x, y, z, p2);
  }
  if (tid < (NSAMP-1)*FPSB) slot[tid] = 0ull;
  if (tid < 4*EMB) stats[tid] = 0.f;
  if (tid >= 1 && tid < NSAMP) sampled[tid] = -1;   // sentinel for workers
  if (tid == 0) sampled[0] = compute_first((unsigned)seed_arr[0]);
}

// ---------------- mega: FPS blocks + group/stats worker blocks ---------------
__global__ __launch_bounds__(1024) void k_mega(
    const float4* __restrict__ xyzw, const float* __restrict__ pts,
    const float* __restrict__ W1, const float* __restrict__ b1,
    unsigned long long* __restrict__ slot, int* __restrict__ sampled,
    int* __restrict__ groups, float* __restrict__ gsum, float* __restrict__ gss) {
  __shared__ __align__(16) char smraw[44160];
  const int t = threadIdx.x;
  if (blockIdx.x < FPSB) {
    // ------------------ FPS role ------------------
    unsigned long long* wred = (unsigned long long*)smraw;       // [2][16]
    volatile int* winLDS = (volatile int*)(smraw + 256);         // [2]
    const int b = blockIdx.x;
    const int T = b*1024 + t;                                    // 0..32767
    const int lane = t & 63, wid = t >> 6;
    float px[FPS_PPT], py[FPS_PPT], pz[FPS_PPT], pd[FPS_PPT];
#pragma unroll
    for (int i = 0; i < FPS_PPT; ++i) {
      float4 p = xyzw[T + 32768*i];
      px[i] = p.x; py[i] = p.y; pz[i] = p.z; pd[i] = __builtin_inff();
    }
    if (t == 0) { winLDS[0] = -1; winLDS[1] = -1; }
    int last = sampled[0];
    __syncthreads();
    for (int it = 0; it < NSAMP-1; ++it) {
      const int p = it & 1;
      float4 cc = xyzw[last];
      unsigned long long best = 1ull;
#pragma unroll
      for (int i = 0; i < FPS_PPT; ++i) {
        int j = T + 32768*i;
        if (j == last) {
          pd[i] = -__builtin_inff();
        } else {
          float dx = __fsub_rn(px[i], cc.x);
          float dy = __fsub_rn(py[i], cc.y);
          float dz = __fsub_rn(pz[i], cc.z);
          float d = __fadd_rn(__fadd_rn(__fmul_rn(dx,dx), __fmul_rn(dy,dy)), __fmul_rn(dz,dz));
          pd[i] = fminf(pd[i], d);
        }
        if (pd[i] >= 0.f) {
          unsigned long long pk = ((unsigned long long)__float_as_uint(pd[i]) << 32)
                                | (unsigned long long)(0xFFFFFFFFu - (unsigned)j);
          best = best > pk ? best : pk;
        }
      }
#pragma unroll
      for (int off = 32; off >= 1; off >>= 1) {
        unsigned long long o = __shfl_xor(best, off, 64);
        best = best > o ? best : o;
      }
      if (lane == 0) wred[p*16 + wid] = best;
      __syncthreads();
      if (wid == 0) {
        if (lane == 0) winLDS[1-p] = -1;   // safe: all waves past prev spin
        unsigned long long m = wred[p*16 + (lane & 15)];
#pragma unroll
        for (int off = 8; off >= 1; off >>= 1) {
          unsigned long long o = __shfl_xor(m, off, 64);
          m = m > o ? m : o;
        }
        if (lane == 0)
          __hip_atomic_store(&slot[it*FPSB + b], m,
                             __ATOMIC_RELAXED, __HIP_MEMORY_SCOPE_AGENT);
        unsigned long long v = 0ull;
        if (lane < FPSB) {
          const unsigned long long* sp = &slot[it*FPSB + lane];
          v = __hip_atomic_load(sp, __ATOMIC_RELAXED, __HIP_MEMORY_SCOPE_AGENT);
          while (v == 0ull)
            v = __hip_atomic_load(sp, __ATOMIC_RELAXED, __HIP_MEMORY_SCOPE_AGENT);
        }
#pragma unroll
        for (int off = 16; off >= 1; off >>= 1) {
          unsigned long long o = __shfl_xor(v, off, 64);
          v = v > o ? v : o;
        }
        v = __shfl(v, 0, 64);
        int win = (int)(0xFFFFFFFFu - (unsigned)(v & 0xFFFFFFFFull));
        if (lane == 0) {
          if (b == 0)
            __hip_atomic_store((unsigned*)&sampled[it+1], (unsigned)win,
                               __ATOMIC_RELAXED, __HIP_MEMORY_SCOPE_AGENT);
          winLDS[p] = win;
        }
        last = win;
      } else {
        int w = winLDS[p];
        while (w == -1) { __builtin_amdgcn_s_sleep(1); w = winLDS[p]; }
        last = w;
      }
    }
  } else {
    // ------------------ worker role: group + bn1 stats ------------------
    unsigned* hist  = (unsigned*)smraw;              // 8192
    unsigned* scan  = (unsigned*)(smraw + 32768);    // 1024
    unsigned* candK = (unsigned*)(smraw + 36864);    // 512
    int*      candI = (int*)(smraw + 38912);         // 512
    float*    feat  = (float*)(smraw + 40960);       // 768
    float*    cf    = (float*)(smraw + 44032);       // 8
    unsigned* ctl   = (unsigned*)(smraw + 44064);    // outcnt, candcnt
    volatile int* binfo = (volatile int*)(smraw + 44080); // B, bef, sid
    const int wkr = blockIdx.x - FPSB;               // 0..223
    for (int s = wkr; s < NSAMP; s += MEGA_BLOCKS - FPSB) {
      if (t == 0) {
        unsigned v = __hip_atomic_load((const unsigned*)&sampled[s],
                        __ATOMIC_RELAXED, __HIP_MEMORY_SCOPE_AGENT);
        while (v == 0xFFFFFFFFu) {
          __builtin_amdgcn_s_sleep(64);
          v = __hip_atomic_load((const unsigned*)&sampled[s],
                  __ATOMIC_RELAXED, __HIP_MEMORY_SCOPE_AGENT);
        }
        binfo[2] = (int)v;
        ctl[0] = 0u; ctl[1] = 0u;
      }
      for (int k = t; k < 8192; k += 1024) hist[k] = 0u;
      __syncthreads();
      const int sid = binfo[2];
      float4 c4 = xyzw[sid];
      const float cx=c4.x, cy=c4.y, cz=c4.z, c2=c4.w;
      for (int i = 0; i < N_PTS/1024; ++i) {
        int j = i*1024 + t;
        float4 p = xyzw[j];
        float dot = __fadd_rn(__fadd_rn(__fmul_rn(cx,p.x),__fmul_rn(cy,p.y)),__fmul_rn(cz,p.z));
        float d = __fsub_rn(__fadd_rn(c2, p.w), __fmul_rn(2.0f, dot));
        unsigned kb = __float_as_uint(d);
        kb ^= ((unsigned)((int)kb >> 31)) | 0x80000000u;
        atomicAdd(&hist[kb >> 19], 1u);
      }
      __syncthreads();
      unsigned ch = 0u;
      for (int k = 0; k < 8; ++k) ch += hist[t*8 + k];
      scan[t] = ch;
      __syncthreads();
      for (int off = 1; off < 1024; off <<= 1) {
        unsigned vv = (t >= off) ? scan[t - off] : 0u;
        __syncthreads();
        scan[t] += vv;
        __syncthreads();
      }
      unsigned inc = scan[t], before = inc - ch;
      if (before < NGRP && inc >= NGRP) {
        unsigned c = before;
        for (int k = 0; k < 8; ++k) {
          unsigned nb = hist[t*8 + k];
          if (c + nb >= NGRP) { binfo[0] = t*8 + k; binfo[1] = (int)c; break; }
          c += nb;
        }
      }
      __syncthreads();
      const unsigned B = (unsigned)binfo[0];
      const int bef = binfo[1];
      for (int i = 0; i < N_PTS/1024; ++i) {
        int j = i*1024 + t;
        float4 p = xyzw[j];
        float dot = __fadd_rn(__fadd_rn(__fmul_rn(cx,p.x),__fmul_rn(cy,p.y)),__fmul_rn(cz,p.z));
        float d = __fsub_rn(__fadd_rn(c2, p.w), __fmul_rn(2.0f, dot));
        unsigned kb = __float_as_uint(d);
        kb ^= ((unsigned)((int)kb >> 31)) | 0x80000000u;
        unsigned bin = kb >> 19;
        if (bin < B) {
          unsigned pos = atomicAdd(&ctl[0], 1u);
          groups[s*NGRP + pos] = j;
        } else if (bin == B) {
          unsigned ci = atomicAdd(&ctl[1], 1u);
          if (ci < GB_CAND) { candK[ci] = kb; candI[ci] = j; }
        }
      }
      __syncthreads();
      int M = ctl[1] < GB_CAND ? (int)ctl[1] : GB_CAND;
      int need = NGRP - bef;
      for (int c = t; c < M; c += 1024) {
        unsigned mk = candK[c]; int mi = candI[c];
        int rank = 0;
        for (int q = 0; q < M; ++q) {
          unsigned qk = candK[q];
          rank += (qk < mk || (qk == mk && candI[q] < mi)) ? 1 : 0;
        }
        if (rank < need) {
          unsigned pos = atomicAdd(&ctl[0], 1u);
          groups[s*NGRP + pos] = candI[c];
        }
      }
      __syncthreads();
      if (t == 0) {
        while (ctl[0] < NGRP) { groups[s*NGRP + ctl[0]] = 0; ctl[0]++; }
      }
      __syncthreads();
      if (t < DIMS) cf[t] = pts[sid*6 + t];
      __syncthreads();
      if (t < NGRP) {
        int g = groups[s*NGRP + t];
#pragma unroll
        for (int k = 0; k < DIMS; ++k) {
          float v = pts[g*6 + k];
          feat[t*12 + k] = v - cf[k];
          feat[t*12 + 6 + k] = v;
        }
      }
      __syncthreads();
      if (t < EMB) {
        float w[12];
#pragma unroll
        for (int k = 0; k < 12; ++k) w[k] = W1[k*EMB + t];
        float b = b1[t];
        float sum = 0.f, ss = 0.f;
        for (int r = 0; r < NGRP; ++r) {
          float y = b;
#pragma unroll
          for (int k = 0; k < 12; ++k) y += feat[r*12+k] * w[k];
          sum += y; ss += y*y;
        }
        atomicAdd(&gsum[t], sum);
        atomicAdd(&gss[t], ss);
      }
      __syncthreads();   // smraw reused next s
    }
  }
}

// ---------------- bn finalize: a = scale*rsqrt(var+eps), c = bias - a*mean --
__global__ __launch_bounds__(EMB) void k_finalize(const float* __restrict__ gsum,
    const float* __restrict__ gss, const float* __restrict__ scale,
    const float* __restrict__ bias, float* __restrict__ ac) {
  int c = threadIdx.x;
  float inv = 1.f / (float)ROWS;
  float mean = gsum[c] * inv;
  float var = gss[c] * inv - mean*mean;
  var = var < 0.f ? 0.f : var;
  float a = scale[c] * rsqrtf(var + EPS_BN);
  ac[c] = a; ac[EMB + c] = bias[c] - mean * a;
}

// ---------------- fused MLP, half-tile version ------------------------------
// 512 threads, h1 staged as two 32-row half-tiles (64 KB) -> ~75 KB LDS
// -> 2 blocks/CU (4 waves/SIMD) instead of 1 (2 waves/SIMD).
// Per-element arithmetic order identical to previous version (k ascending).
__global__ __launch_bounds__(512, 4) void k_mlp(const float* __restrict__ pts,
    const int* __restrict__ sampled, const int* __restrict__ groups,
    const float* __restrict__ W1, const float* __restrict__ b1,
    const float* __restrict__ ac1, const float* __restrict__ W2,
    const float* __restrict__ b2, const float* __restrict__ scale2,
    float* __restrict__ gsum, float* __restrict__ gss,
    float* __restrict__ y2sel) {
  const int s = blockIdx.x, t = threadIdx.x;
  extern __shared__ float sm[];
  float* feat = sm;                 // 768
  float* cf   = sm + 768;           // 8
  float* red  = sm + 776;           // 2048
  float* h1   = sm + 2824;          // 32*512 = 16384
  if (t < DIMS) cf[t] = pts[sampled[s]*6 + t];
  __syncthreads();
  if (t < NGRP) {
    int g = groups[s*NGRP + t];
#pragma unroll
    for (int k = 0; k < DIMS; ++k) {
      float v = pts[g*6 + k];
      feat[t*12+k]   = v - cf[k];
      feat[t*12+6+k] = v;
    }
  }
  __syncthreads();
  const int lane = t & 63, wid = t >> 6;   // 8 waves; wave owns 4 rows/half
  float psum[8], pss[8], pmax[8], pmin[8];
#pragma unroll
  for (int j = 0; j < 8; ++j) {
    psum[j]=0.f; pss[j]=0.f; pmax[j]=-__builtin_inff(); pmin[j]=__builtin_inff();
  }
  for (int half = 0; half < 2; ++half) {
    const int rbase = half * 32;
    {  // GEMM1 + bn1 + relu for this half's 32 rows (thread t = column t)
      float w[12];
#pragma unroll
      for (int k = 0; k < 12; ++k) w[k] = W1[k*EMB + t];
      float b = b1[t], a1 = ac1[t], c1 = ac1[EMB + t];
      for (int r = 0; r < 32; ++r) {
        float y = b;
#pragma unroll
        for (int k = 0; k < 12; ++k) y += feat[(rbase+r)*12+k] * w[k];
        float hv = a1*y + c1;
        h1[r*EMB + t] = hv > 0.f ? hv : 0.f;
      }
    }
    __syncthreads();
    float acc[4][8];
    {
      float4 blo = *(const float4*)&b2[lane*8];
      float4 bhi = *(const float4*)&b2[lane*8 + 4];
      float b2r[8] = {blo.x, blo.y, blo.z, blo.w, bhi.x, bhi.y, bhi.z, bhi.w};
#pragma unroll
      for (int i = 0; i < 4; ++i)
#pragma unroll
        for (int j = 0; j < 8; ++j) acc[i][j] = b2r[j];
    }
    const float* h1r = h1 + (wid*4)*EMB;
    for (int k = 0; k < EMB; k += 4) {
      float hk[4][4];
#pragma unroll
      for (int i = 0; i < 4; ++i) {
        float4 hv4 = *(const float4*)&h1r[i*EMB + k];   // LDS b128 broadcast
        hk[i][0]=hv4.x; hk[i][1]=hv4.y; hk[i][2]=hv4.z; hk[i][3]=hv4.w;
      }
#pragma unroll
      for (int kk = 0; kk < 4; ++kk) {
        float4 wlo = *(const float4*)&W2[(k+kk)*EMB + lane*8];
        float4 whi = *(const float4*)&W2[(k+kk)*EMB + lane*8 + 4];
        float wv[8] = {wlo.x, wlo.y, wlo.z, wlo.w, whi.x, whi.y, whi.z, whi.w};
#pragma unroll
        for (int i = 0; i < 4; ++i)
#pragma unroll
          for (int j = 0; j < 8; ++j) acc[i][j] += hk[i][kk] * wv[j];
      }
    }
#pragma unroll
    for (int j = 0; j < 8; ++j) {
#pragma unroll
      for (int i = 0; i < 4; ++i) {
        float v = acc[i][j];
        psum[j] += v; pss[j] += v*v;
        pmax[j] = fmaxf(pmax[j], v); pmin[j] = fminf(pmin[j], v);
      }
    }
    __syncthreads();   // before next half overwrites h1
  }
  float* rsum = red; float* rss = red+512; float* rmx = red+1024; float* rmn = red+1536;
  for (int w = 0; w < 8; ++w) {
    if (wid == w) {
#pragma unroll
      for (int j = 0; j < 8; ++j) {
        int c = lane*8 + j;
        if (w == 0) { rsum[c]=psum[j]; rss[c]=pss[j]; rmx[c]=pmax[j]; rmn[c]=pmin[j]; }
        else { rsum[c]+=psum[j]; rss[c]+=pss[j];
               rmx[c]=fmaxf(rmx[c],pmax[j]); rmn[c]=fminf(rmn[c],pmin[j]); }
      }
    }
    __syncthreads();
  }
  if (t < EMB) {
    atomicAdd(&gsum[t], rsum[t]);
    atomicAdd(&gss[t], rss[t]);
    y2sel[s*EMB + t] = (scale2[t] >= 0.f) ? rmx[t] : rmn[t];
  }
}

// ---------------- epilogue: bn2+relu on pooled extremum ---------------------
__global__ __launch_bounds__(256) void k_out(const float* __restrict__ y2sel,
    const float* __restrict__ ac2, float* __restrict__ out) {
  int i = blockIdx.x*256 + threadIdx.x;
  int c = i & (EMB-1);
  float a = ac2[c], cc = ac2[EMB + c];
  float v = a*y2sel[i] + cc;
  out[i] = v > 0.f ? v : 0.f;
}

extern "C" void kernel_launch(void* const* d_in, const int* in_sizes, int n_in,
                              void* d_out, int out_size, void* d_ws, size_t ws_size,
                              hipStream_t stream) {
  const float* pts    = (const float*)d_in[0];
  const float* W1     = (const float*)d_in[1];
  const float* b1     = (const float*)d_in[2];
  const float* scale1 = (const float*)d_in[3];
  const float* bias1  = (const float*)d_in[4];
  const float* W2     = (const float*)d_in[5];
  const float* b2     = (const float*)d_in[6];
  const float* scale2 = (const float*)d_in[7];
  const float* bias2  = (const float*)d_in[8];
  const int*   seed   = (const int*)d_in[9];
  float* out = (float*)d_out;

  char* ws = (char*)d_ws;
  int*    sampled = (int*)(ws);
  int*    groups  = (int*)(ws + 8192);
  float4* xyzw    = (float4*)(ws + 532480);
  float*  stats   = (float*)(ws + 1581056);
  float* gsum1 = stats, *gss1 = stats+512, *gsum2 = stats+1024, *gss2 = stats+1536;
  float*  ac1     = (float*)(ws + 1589248);
  float*  ac2     = (float*)(ws + 1593344);
  float*  y2sel   = (float*)(ws + 1597440);
  // slot aliases y2sel (disjoint lifetime): 2047*32 u64 = 524KB < 4MB region
  unsigned long long* slot = (unsigned long long*)(ws + 1597440);

  k_init<<<256, 256, 0, stream>>>(pts, seed, slot, stats, xyzw, sampled);
  k_mega<<<MEGA_BLOCKS, 1024, 0, stream>>>(xyzw, pts, W1, b1, slot, sampled,
                                           groups, gsum1, gss1);
  k_finalize<<<1, EMB, 0, stream>>>(gsum1, gss1, scale1, bias1, ac1);
  size_t mlp_lds = (size_t)(2824 + 32*EMB) * sizeof(float);   // ~75 KB
  k_mlp<<<NSAMP, 512, mlp_lds, stream>>>(pts, sampled, groups, W1, b1, ac1,
                                         W2, b2, scale2, gsum2, gss2, y2sel);
  k_finalize<<<1, EMB, 0, stream>>>(gsum2, gss2, scale2, bias2, ac2);
  k_out<<<(out_size+255)/256, 256, 0, stream>>>(y2sel, ac2, out);
}

// Round 8
// 6718.575 us; speedup vs baseline: 1.1416x; 1.1416x over previous
//
#include <hip/hip_runtime.h>
#include <stdint.h>

#define N_PTS 65536
#define DIMS 6
#define NSAMP 2048
#define NGRP 64
#define EMB 512
#define ROWS (NSAMP*NGRP)
#define EPS_BN 1e-5f

#define FIRST_MODE 0

// ---------------- Threefry-2x32, 20 rounds (JAX-compatible) ----------------
__device__ __forceinline__ void tf2x32(unsigned k0, unsigned k1, unsigned &x0, unsigned &x1) {
  unsigned ks[3] = {k0, k1, k0 ^ k1 ^ 0x1BD11BDAu};
  const unsigned R[8] = {13,15,26,6,17,29,16,24};
  x0 += ks[0]; x1 += ks[1];
#pragma unroll
  for (int g = 0; g < 5; ++g) {
#pragma unroll
    for (int j = 0; j < 4; ++j) {
      unsigned r = R[(g & 1) * 4 + j];
      x0 += x1;
      x1 = (x1 << r) | (x1 >> (32 - r));
      x1 ^= x0;
    }
    x0 += ks[(g + 1) % 3];
    x1 += ks[(g + 2) % 3] + (unsigned)(g + 1);
  }
}

__device__ __forceinline__ int compute_first(unsigned seed) {
  unsigned k0 = 0u, k1 = seed;
  unsigned s0, s1;
#if (FIRST_MODE == 0) || (FIRST_MODE == 1)
  { unsigned a0 = 0u, a1 = 1u; tf2x32(k0, k1, a0, a1); s0 = a0; s1 = a1; }
#else
  { unsigned p0 = 0u, p1 = 2u; tf2x32(k0, k1, p0, p1);
    unsigned q0 = 1u, q1 = 3u; tf2x32(k0, k1, q0, q1);
    s0 = p1; s1 = q1; }
#endif
  unsigned b0 = 0u, b1v = 0u; tf2x32(s0, s1, b0, b1v);
#if (FIRST_MODE == 0) || (FIRST_MODE == 3)
  unsigned bits = b0 ^ b1v;
#else
  unsigned bits = b0;
#endif
  return (int)(bits & 0xFFFFu);
}

// ---------------- geometry ---------------------------------------------------
#define FPSB 16                      // FPS blocks (16 slots = two 64B lines/iter)
#define MEGA_BLOCKS 256              // 16 FPS + 240 workers; all co-resident
#define FPS_PPT 4                    // 65536 / (16*1024)
#define GB_CAND 512

// ---------------- init -------------------------------------------------------
__global__ __launch_bounds__(256) void k_init(const float* __restrict__ pts,
    const int* __restrict__ seed_arr, unsigned long long* __restrict__ slot,
    float* __restrict__ stats, float4* __restrict__ xyzw,
    int* __restrict__ sampled) {
  int tid = blockIdx.x * 256 + threadIdx.x;        // 65536 threads
  if (tid < N_PTS) {
    float x = pts[tid*6], y = pts[tid*6+1], z = pts[tid*6+2];
    float p2 = __fadd_rn(__fadd_rn(__fmul_rn(x,x), __fmul_rn(y,y)), __fmul_rn(z,z));
    xyzw[tid] = make_float4(x, y, z, p2);
  }
  if (tid < (NSAMP-1)*FPSB) slot[tid] = 0ull;
  if (tid < 4*EMB) stats[tid] = 0.f;
  if (tid >= 1 && tid < NSAMP) sampled[tid] = -1;   // sentinel for workers
  if (tid == 0) sampled[0] = compute_first((unsigned)seed_arr[0]);
}

// ---------------- mega: FPS blocks + group/stats worker blocks ---------------
// (identical to the measured-best R6 configuration: FPSB=16, per-iter 2.43us)
__global__ __launch_bounds__(1024) void k_mega(
    const float4* __restrict__ xyzw, const float* __restrict__ pts,
    const float* __restrict__ W1, const float* __restrict__ b1,
    unsigned long long* __restrict__ slot, int* __restrict__ sampled,
    int* __restrict__ groups, float* __restrict__ gsum, float* __restrict__ gss) {
  __shared__ __align__(16) char smraw[44160];
  const int t = threadIdx.x;
  if (blockIdx.x < FPSB) {
    // ------------------ FPS role ------------------
    unsigned long long* wred = (unsigned long long*)smraw;       // [2][16]
    volatile int* winLDS = (volatile int*)(smraw + 256);         // [2]
    const int b = blockIdx.x;
    const int T = b*1024 + t;                                    // 0..16383
    const int lane = t & 63, wid = t >> 6;
    float px[FPS_PPT], py[FPS_PPT], pz[FPS_PPT], pd[FPS_PPT];
#pragma unroll
    for (int i = 0; i < FPS_PPT; ++i) {
      float4 p = xyzw[T + 16384*i];
      px[i] = p.x; py[i] = p.y; pz[i] = p.z; pd[i] = __builtin_inff();
    }
    if (t == 0) { winLDS[0] = -1; winLDS[1] = -1; }
    int last = sampled[0];
    __syncthreads();
    for (int it = 0; it < NSAMP-1; ++it) {
      const int p = it & 1;
      float4 cc = xyzw[last];
      unsigned long long best = 1ull;
#pragma unroll
      for (int i = 0; i < FPS_PPT; ++i) {
        int j = T + 16384*i;
        if (j == last) {
          pd[i] = -__builtin_inff();
        } else {
          float dx = __fsub_rn(px[i], cc.x);
          float dy = __fsub_rn(py[i], cc.y);
          float dz = __fsub_rn(pz[i], cc.z);
          float d = __fadd_rn(__fadd_rn(__fmul_rn(dx,dx), __fmul_rn(dy,dy)), __fmul_rn(dz,dz));
          pd[i] = fminf(pd[i], d);
        }
        if (pd[i] >= 0.f) {
          unsigned long long pk = ((unsigned long long)__float_as_uint(pd[i]) << 32)
                                | (unsigned long long)(0xFFFFFFFFu - (unsigned)j);
          best = best > pk ? best : pk;
        }
      }
#pragma unroll
      for (int off = 32; off >= 1; off >>= 1) {
        unsigned long long o = __shfl_xor(best, off, 64);
        best = best > o ? best : o;
      }
      if (lane == 0) wred[p*16 + wid] = best;
      __syncthreads();
      if (wid == 0) {
        if (lane == 0) winLDS[1-p] = -1;   // safe: all waves past prev spin
        unsigned long long m = wred[p*16 + (lane & 15)];
#pragma unroll
        for (int off = 8; off >= 1; off >>= 1) {
          unsigned long long o = __shfl_xor(m, off, 64);
          m = m > o ? m : o;
        }
        if (lane == 0)
          __hip_atomic_store(&slot[it*FPSB + b], m,
                             __ATOMIC_RELAXED, __HIP_MEMORY_SCOPE_AGENT);
        unsigned long long v = 0ull;
        if (lane < FPSB) {
          const unsigned long long* sp = &slot[it*FPSB + lane];
          v = __hip_atomic_load(sp, __ATOMIC_RELAXED, __HIP_MEMORY_SCOPE_AGENT);
          while (v == 0ull)
            v = __hip_atomic_load(sp, __ATOMIC_RELAXED, __HIP_MEMORY_SCOPE_AGENT);
        }
#pragma unroll
        for (int off = 8; off >= 1; off >>= 1) {
          unsigned long long o = __shfl_xor(v, off, 64);
          v = v > o ? v : o;
        }
        v = __shfl(v, 0, 64);
        int win = (int)(0xFFFFFFFFu - (unsigned)(v & 0xFFFFFFFFull));
        if (lane == 0) {
          if (b == 0)
            __hip_atomic_store((unsigned*)&sampled[it+1], (unsigned)win,
                               __ATOMIC_RELAXED, __HIP_MEMORY_SCOPE_AGENT);
          winLDS[p] = win;
        }
        last = win;
      } else {
        int w = winLDS[p];
        while (w == -1) { __builtin_amdgcn_s_sleep(1); w = winLDS[p]; }
        last = w;
      }
    }
  } else {
    // ------------------ worker role: group + bn1 stats ------------------
    unsigned* hist  = (unsigned*)smraw;              // 8192
    unsigned* scan  = (unsigned*)(smraw + 32768);    // 1024
    unsigned* candK = (unsigned*)(smraw + 36864);    // 512
    int*      candI = (int*)(smraw + 38912);         // 512
    float*    feat  = (float*)(smraw + 40960);       // 768
    float*    cf    = (float*)(smraw + 44032);       // 8
    unsigned* ctl   = (unsigned*)(smraw + 44064);    // outcnt, candcnt
    volatile int* binfo = (volatile int*)(smraw + 44080); // B, bef, sid
    const int wkr = blockIdx.x - FPSB;               // 0..239
    for (int s = wkr; s < NSAMP; s += MEGA_BLOCKS - FPSB) {
      if (t == 0) {
        unsigned v = __hip_atomic_load((const unsigned*)&sampled[s],
                        __ATOMIC_RELAXED, __HIP_MEMORY_SCOPE_AGENT);
        while (v == 0xFFFFFFFFu) {
          __builtin_amdgcn_s_sleep(64);
          v = __hip_atomic_load((const unsigned*)&sampled[s],
                  __ATOMIC_RELAXED, __HIP_MEMORY_SCOPE_AGENT);
        }
        binfo[2] = (int)v;
        ctl[0] = 0u; ctl[1] = 0u;
      }
      for (int k = t; k < 8192; k += 1024) hist[k] = 0u;
      __syncthreads();
      const int sid = binfo[2];
      float4 c4 = xyzw[sid];
      const float cx=c4.x, cy=c4.y, cz=c4.z, c2=c4.w;
      for (int i = 0; i < N_PTS/1024; ++i) {
        int j = i*1024 + t;
        float4 p = xyzw[j];
        float dot = __fadd_rn(__fadd_rn(__fmul_rn(cx,p.x),__fmul_rn(cy,p.y)),__fmul_rn(cz,p.z));
        float d = __fsub_rn(__fadd_rn(c2, p.w), __fmul_rn(2.0f, dot));
        unsigned kb = __float_as_uint(d);
        kb ^= ((unsigned)((int)kb >> 31)) | 0x80000000u;
        atomicAdd(&hist[kb >> 19], 1u);
      }
      __syncthreads();
      unsigned ch = 0u;
      for (int k = 0; k < 8; ++k) ch += hist[t*8 + k];
      scan[t] = ch;
      __syncthreads();
      for (int off = 1; off < 1024; off <<= 1) {
        unsigned vv = (t >= off) ? scan[t - off] : 0u;
        __syncthreads();
        scan[t] += vv;
        __syncthreads();
      }
      unsigned inc = scan[t], before = inc - ch;
      if (before < NGRP && inc >= NGRP) {
        unsigned c = before;
        for (int k = 0; k < 8; ++k) {
          unsigned nb = hist[t*8 + k];
          if (c + nb >= NGRP) { binfo[0] = t*8 + k; binfo[1] = (int)c; break; }
          c += nb;
        }
      }
      __syncthreads();
      const unsigned B = (unsigned)binfo[0];
      const int bef = binfo[1];
      for (int i = 0; i < N_PTS/1024; ++i) {
        int j = i*1024 + t;
        float4 p = xyzw[j];
        float dot = __fadd_rn(__fadd_rn(__fmul_rn(cx,p.x),__fmul_rn(cy,p.y)),__fmul_rn(cz,p.z));
        float d = __fsub_rn(__fadd_rn(c2, p.w), __fmul_rn(2.0f, dot));
        unsigned kb = __float_as_uint(d);
        kb ^= ((unsigned)((int)kb >> 31)) | 0x80000000u;
        unsigned bin = kb >> 19;
        if (bin < B) {
          unsigned pos = atomicAdd(&ctl[0], 1u);
          groups[s*NGRP + pos] = j;
        } else if (bin == B) {
          unsigned ci = atomicAdd(&ctl[1], 1u);
          if (ci < GB_CAND) { candK[ci] = kb; candI[ci] = j; }
        }
      }
      __syncthreads();
      int M = ctl[1] < GB_CAND ? (int)ctl[1] : GB_CAND;
      int need = NGRP - bef;
      for (int c = t; c < M; c += 1024) {
        unsigned mk = candK[c]; int mi = candI[c];
        int rank = 0;
        for (int q = 0; q < M; ++q) {
          unsigned qk = candK[q];
          rank += (qk < mk || (qk == mk && candI[q] < mi)) ? 1 : 0;
        }
        if (rank < need) {
          unsigned pos = atomicAdd(&ctl[0], 1u);
          groups[s*NGRP + pos] = candI[c];
        }
      }
      __syncthreads();
      if (t == 0) {
        while (ctl[0] < NGRP) { groups[s*NGRP + ctl[0]] = 0; ctl[0]++; }
      }
      __syncthreads();
      if (t < DIMS) cf[t] = pts[sid*6 + t];
      __syncthreads();
      if (t < NGRP) {
        int g = groups[s*NGRP + t];
#pragma unroll
        for (int k = 0; k < DIMS; ++k) {
          float v = pts[g*6 + k];
          feat[t*12 + k] = v - cf[k];
          feat[t*12 + 6 + k] = v;
        }
      }
      __syncthreads();
      if (t < EMB) {
        float w[12];
#pragma unroll
        for (int k = 0; k < 12; ++k) w[k] = W1[k*EMB + t];
        float b = b1[t];
        float sum = 0.f, ss = 0.f;
        for (int r = 0; r < NGRP; ++r) {
          float y = b;
#pragma unroll
          for (int k = 0; k < 12; ++k) y += feat[r*12+k] * w[k];
          sum += y; ss += y*y;
        }
        atomicAdd(&gsum[t], sum);
        atomicAdd(&gss[t], ss);
      }
      __syncthreads();   // smraw reused next s
    }
  }
}

// ---------------- bn finalize: a = scale*rsqrt(var+eps), c = bias - a*mean --
__global__ __launch_bounds__(EMB) void k_finalize(const float* __restrict__ gsum,
    const float* __restrict__ gss, const float* __restrict__ scale,
    const float* __restrict__ bias, float* __restrict__ ac) {
  int c = threadIdx.x;
  float inv = 1.f / (float)ROWS;
  float mean = gsum[c] * inv;
  float var = gss[c] * inv - mean*mean;
  var = var < 0.f ? 0.f : var;
  float a = scale[c] * rsqrtf(var + EPS_BN);
  ac[c] = a; ac[EMB + c] = bias[c] - mean * a;
}

// ---------------- fused MLP, wave-column-sliced GEMM2 ------------------------
// 512 threads (8 waves). Wave w owns W2 columns [64w, 64w+64): W2 is read
// exactly once per block per half (8x less L1/L2 traffic than row-broadcast).
// lane = 8*rg + cg: owns rows {rg*4+i} x cols {64w + cg*8 + j}.
// h1 stored TRANSPOSED, stride 33 (h1T[k][r]): GEMM2 fragment = one
// conflict-free ds_read_b128 per k (rg*4 bank-starts tile all 32 banks);
// GEMM1 write pattern (t*33 + r) is 2-way aliased = free.
// Per-(r,c) k-accumulation order identical to previous rounds -> y2 bitwise
// unchanged; only stats/pool reduction order differs (below threshold).
#define H1T_S 33
__global__ __launch_bounds__(512, 4) void k_mlp(const float* __restrict__ pts,
    const int* __restrict__ sampled, const int* __restrict__ groups,
    const float* __restrict__ W1, const float* __restrict__ b1,
    const float* __restrict__ ac1, const float* __restrict__ W2,
    const float* __restrict__ b2, const float* __restrict__ scale2,
    float* __restrict__ gsum, float* __restrict__ gss,
    float* __restrict__ y2sel) {
  const int s = blockIdx.x, t = threadIdx.x;
  extern __shared__ float sm[];
  float* feat = sm;                 // 768
  float* cf   = sm + 768;           // 8
  float* h1T  = sm + 776;           // 512*33 = 16896  (~70.7 KB total)
  if (t < DIMS) cf[t] = pts[sampled[s]*6 + t];
  __syncthreads();
  if (t < NGRP) {
    int g = groups[s*NGRP + t];
#pragma unroll
    for (int k = 0; k < DIMS; ++k) {
      float v = pts[g*6 + k];
      feat[t*12+k]   = v - cf[k];
      feat[t*12+6+k] = v;
    }
  }
  __syncthreads();
  const int lane = t & 63, wid = t >> 6;
  const int rg = lane >> 3, cg = lane & 7;
  const int col0 = wid*64 + cg*8;
  float psum[8], pss[8], pmax[8], pmin[8];
#pragma unroll
  for (int j = 0; j < 8; ++j) {
    psum[j]=0.f; pss[j]=0.f; pmax[j]=-__builtin_inff(); pmin[j]=__builtin_inff();
  }
  float b2r[8];
  {
    float4 blo = *(const float4*)&b2[col0];
    float4 bhi = *(const float4*)&b2[col0 + 4];
    b2r[0]=blo.x; b2r[1]=blo.y; b2r[2]=blo.z; b2r[3]=blo.w;
    b2r[4]=bhi.x; b2r[5]=bhi.y; b2r[6]=bhi.z; b2r[7]=bhi.w;
  }
  for (int half = 0; half < 2; ++half) {
    const int rbase = half * 32;
    {  // GEMM1 + bn1 + relu: thread t = column t, 32 rows, write transposed
      float w[12];
#pragma unroll
      for (int k = 0; k < 12; ++k) w[k] = W1[k*EMB + t];
      float b = b1[t], a1 = ac1[t], c1 = ac1[EMB + t];
      for (int r = 0; r < 32; ++r) {
        float y = b;
#pragma unroll
        for (int k = 0; k < 12; ++k) y += feat[(rbase+r)*12+k] * w[k];
        float hv = a1*y + c1;
        h1T[t*H1T_S + r] = hv > 0.f ? hv : 0.f;
      }
    }
    __syncthreads();
    float acc[4][8];
#pragma unroll
    for (int i = 0; i < 4; ++i)
#pragma unroll
      for (int j = 0; j < 8; ++j) acc[i][j] = b2r[j];
    for (int k = 0; k < EMB; k += 4) {
      float4 hv4[4];
#pragma unroll
      for (int kk = 0; kk < 4; ++kk)
        hv4[kk] = *(const float4*)&h1T[(k+kk)*H1T_S + rg*4];   // rows rg*4..+3
#pragma unroll
      for (int kk = 0; kk < 4; ++kk) {
        float4 wlo = *(const float4*)&W2[(k+kk)*EMB + col0];
        float4 whi = *(const float4*)&W2[(k+kk)*EMB + col0 + 4];
        float wv[8] = {wlo.x, wlo.y, wlo.z, wlo.w, whi.x, whi.y, whi.z, whi.w};
        float hk[4] = {hv4[kk].x, hv4[kk].y, hv4[kk].z, hv4[kk].w};
#pragma unroll
        for (int i = 0; i < 4; ++i)
#pragma unroll
          for (int j = 0; j < 8; ++j) acc[i][j] += hk[i] * wv[j];
      }
    }
#pragma unroll
    for (int j = 0; j < 8; ++j) {
#pragma unroll
      for (int i = 0; i < 4; ++i) {
        float v = acc[i][j];
        psum[j] += v; pss[j] += v*v;
        pmax[j] = fmaxf(pmax[j], v); pmin[j] = fminf(pmin[j], v);
      }
    }
    __syncthreads();   // before next half overwrites h1T
  }
  // reduce across rg (lane bits 3..5); waves own disjoint columns
#pragma unroll
  for (int j = 0; j < 8; ++j) {
#pragma unroll
    for (int off = 8; off <= 32; off <<= 1) {
      psum[j] += __shfl_xor(psum[j], off, 64);
      pss[j]  += __shfl_xor(pss[j],  off, 64);
      pmax[j] = fmaxf(pmax[j], __shfl_xor(pmax[j], off, 64));
      pmin[j] = fminf(pmin[j], __shfl_xor(pmin[j], off, 64));
    }
  }
  if (rg == 0) {
#pragma unroll
    for (int j = 0; j < 8; ++j) {
      int c = col0 + j;
      atomicAdd(&gsum[c], psum[j]);
      atomicAdd(&gss[c], pss[j]);
      y2sel[s*EMB + c] = (scale2[c] >= 0.f) ? pmax[j] : pmin[j];
    }
  }
}

// ---------------- epilogue: bn2+relu on pooled extremum ---------------------
__global__ __launch_bounds__(256) void k_out(const float* __restrict__ y2sel,
    const float* __restrict__ ac2, float* __restrict__ out) {
  int i = blockIdx.x*256 + threadIdx.x;
  int c = i & (EMB-1);
  float a = ac2[c], cc = ac2[EMB + c];
  float v = a*y2sel[i] + cc;
  out[i] = v > 0.f ? v : 0.f;
}

extern "C" void kernel_launch(void* const* d_in, const int* in_sizes, int n_in,
                              void* d_out, int out_size, void* d_ws, size_t ws_size,
                              hipStream_t stream) {
  const float* pts    = (const float*)d_in[0];
  const float* W1     = (const float*)d_in[1];
  const float* b1     = (const float*)d_in[2];
  const float* scale1 = (const float*)d_in[3];
  const float* bias1  = (const float*)d_in[4];
  const float* W2     = (const float*)d_in[5];
  const float* b2     = (const float*)d_in[6];
  const float* scale2 = (const float*)d_in[7];
  const float* bias2  = (const float*)d_in[8];
  const int*   seed   = (const int*)d_in[9];
  float* out = (float*)d_out;

  char* ws = (char*)d_ws;
  int*    sampled = (int*)(ws);
  int*    groups  = (int*)(ws + 8192);
  float4* xyzw    = (float4*)(ws + 532480);
  float*  stats   = (float*)(ws + 1581056);
  float* gsum1 = stats, *gss1 = stats+512, *gsum2 = stats+1024, *gss2 = stats+1536;
  float*  ac1     = (float*)(ws + 1589248);
  float*  ac2     = (float*)(ws + 1593344);
  float*  y2sel   = (float*)(ws + 1597440);
  // slot aliases y2sel (disjoint lifetime): 2047*16 u64 = 262KB < 4MB region
  unsigned long long* slot = (unsigned long long*)(ws + 1597440);

  k_init<<<256, 256, 0, stream>>>(pts, seed, slot, stats, xyzw, sampled);
  k_mega<<<MEGA_BLOCKS, 1024, 0, stream>>>(xyzw, pts, W1, b1, slot, sampled,
                                           groups, gsum1, gss1);
  k_finalize<<<1, EMB, 0, stream>>>(gsum1, gss1, scale1, bias1, ac1);
  size_t mlp_lds = (size_t)(776 + EMB*H1T_S) * sizeof(float);   // ~70.7 KB
  k_mlp<<<NSAMP, 512, mlp_lds, stream>>>(pts, sampled, groups, W1, b1, ac1,
                                         W2, b2, scale2, gsum2, gss2, y2sel);
  k_finalize<<<1, EMB, 0, stream>>>(gsum2, gss2, scale2, bias2, ac2);
  k_out<<<(out_size+255)/256, 256, 0, stream>>>(y2sel, ac2, out);
}

// Round 9
// 5199.000 us; speedup vs baseline: 1.4753x; 1.2923x over previous
//
#include <hip/hip_runtime.h>
#include <stdint.h>

#define N_PTS 65536
#define DIMS 6
#define NSAMP 2048
#define NGRP 64
#define EMB 512
#define ROWS (NSAMP*NGRP)
#define EPS_BN 1e-5f

#define FIRST_MODE 0

typedef __attribute__((ext_vector_type(8))) short short8;
typedef __attribute__((ext_vector_type(4))) float float4v;

__device__ __forceinline__ unsigned short f2bf(float f) {
  unsigned u = __float_as_uint(f);
  u += 0x7FFFu + ((u >> 16) & 1u);   // RNE
  return (unsigned short)(u >> 16);
}

// ---------------- Threefry-2x32, 20 rounds (JAX-compatible) ----------------
__device__ __forceinline__ void tf2x32(unsigned k0, unsigned k1, unsigned &x0, unsigned &x1) {
  unsigned ks[3] = {k0, k1, k0 ^ k1 ^ 0x1BD11BDAu};
  const unsigned R[8] = {13,15,26,6,17,29,16,24};
  x0 += ks[0]; x1 += ks[1];
#pragma unroll
  for (int g = 0; g < 5; ++g) {
#pragma unroll
    for (int j = 0; j < 4; ++j) {
      unsigned r = R[(g & 1) * 4 + j];
      x0 += x1;
      x1 = (x1 << r) | (x1 >> (32 - r));
      x1 ^= x0;
    }
    x0 += ks[(g + 1) % 3];
    x1 += ks[(g + 2) % 3] + (unsigned)(g + 1);
  }
}

__device__ __forceinline__ int compute_first(unsigned seed) {
  unsigned k0 = 0u, k1 = seed;
  unsigned s0, s1;
#if (FIRST_MODE == 0) || (FIRST_MODE == 1)
  { unsigned a0 = 0u, a1 = 1u; tf2x32(k0, k1, a0, a1); s0 = a0; s1 = a1; }
#else
  { unsigned p0 = 0u, p1 = 2u; tf2x32(k0, k1, p0, p1);
    unsigned q0 = 1u, q1 = 3u; tf2x32(k0, k1, q0, q1);
    s0 = p1; s1 = q1; }
#endif
  unsigned b0 = 0u, b1v = 0u; tf2x32(s0, s1, b0, b1v);
#if (FIRST_MODE == 0) || (FIRST_MODE == 3)
  unsigned bits = b0 ^ b1v;
#else
  unsigned bits = b0;
#endif
  return (int)(bits & 0xFFFFu);
}

// ---------------- geometry ---------------------------------------------------
#define FPSB 16                      // FPS blocks (16 slots = two 64B lines/iter)
#define MEGA_BLOCKS 256              // 16 FPS + 240 workers; all co-resident
#define FPS_PPT 4                    // 65536 / (16*1024)
#define GB_CAND 512
#define H1B_S 520                    // bf16 h1 LDS row stride (bank-benign)

// ---------------- init: xyzw, slots, stats, W2T(bf16), first idx ------------
__global__ __launch_bounds__(256) void k_init(const float* __restrict__ pts,
    const float* __restrict__ W2, const int* __restrict__ seed_arr,
    unsigned long long* __restrict__ slot, float* __restrict__ stats,
    float* __restrict__ st2, unsigned short* __restrict__ W2T,
    float4* __restrict__ xyzw, int* __restrict__ sampled) {
  int tid = blockIdx.x * 256 + threadIdx.x;        // 65536 threads
  if (tid < N_PTS) {
    float x = pts[tid*6], y = pts[tid*6+1], z = pts[tid*6+2];
    float p2 = __fadd_rn(__fadd_rn(__fmul_rn(x,x), __fmul_rn(y,y)), __fmul_rn(z,z));
    xyzw[tid] = make_float4(x, y, z, p2);
  }
#pragma unroll
  for (int i = 0; i < 4; ++i) {      // W2T[c][k] = bf16(W2[k][c]); writes coalesced
    int e = tid + i*65536;
    int c = e >> 9, k = e & 511;
    W2T[e] = f2bf(W2[k*EMB + c]);
  }
  if (tid < (NSAMP-1)*FPSB) slot[tid] = 0ull;
  if (tid < 4*EMB) stats[tid] = 0.f;
  if (tid < 32*1024) st2[tid] = 0.f;               // sliced bn2 stats
  if (tid >= 1 && tid < NSAMP) sampled[tid] = -1;  // sentinel for workers
  if (tid == 0) sampled[0] = compute_first((unsigned)seed_arr[0]);
}

// ---------------- mega: FPS blocks + group/stats worker blocks ---------------
// (identical to the measured-best R6 configuration: FPSB=16, per-iter 2.43us)
__global__ __launch_bounds__(1024) void k_mega(
    const float4* __restrict__ xyzw, const float* __restrict__ pts,
    const float* __restrict__ W1, const float* __restrict__ b1,
    unsigned long long* __restrict__ slot, int* __restrict__ sampled,
    int* __restrict__ groups, float* __restrict__ gsum, float* __restrict__ gss) {
  __shared__ __align__(16) char smraw[44160];
  const int t = threadIdx.x;
  if (blockIdx.x < FPSB) {
    // ------------------ FPS role ------------------
    unsigned long long* wred = (unsigned long long*)smraw;       // [2][16]
    volatile int* winLDS = (volatile int*)(smraw + 256);         // [2]
    const int b = blockIdx.x;
    const int T = b*1024 + t;                                    // 0..16383
    const int lane = t & 63, wid = t >> 6;
    float px[FPS_PPT], py[FPS_PPT], pz[FPS_PPT], pd[FPS_PPT];
#pragma unroll
    for (int i = 0; i < FPS_PPT; ++i) {
      float4 p = xyzw[T + 16384*i];
      px[i] = p.x; py[i] = p.y; pz[i] = p.z; pd[i] = __builtin_inff();
    }
    if (t == 0) { winLDS[0] = -1; winLDS[1] = -1; }
    int last = sampled[0];
    __syncthreads();
    for (int it = 0; it < NSAMP-1; ++it) {
      const int p = it & 1;
      float4 cc = xyzw[last];
      unsigned long long best = 1ull;
#pragma unroll
      for (int i = 0; i < FPS_PPT; ++i) {
        int j = T + 16384*i;
        if (j == last) {
          pd[i] = -__builtin_inff();
        } else {
          float dx = __fsub_rn(px[i], cc.x);
          float dy = __fsub_rn(py[i], cc.y);
          float dz = __fsub_rn(pz[i], cc.z);
          float d = __fadd_rn(__fadd_rn(__fmul_rn(dx,dx), __fmul_rn(dy,dy)), __fmul_rn(dz,dz));
          pd[i] = fminf(pd[i], d);
        }
        if (pd[i] >= 0.f) {
          unsigned long long pk = ((unsigned long long)__float_as_uint(pd[i]) << 32)
                                | (unsigned long long)(0xFFFFFFFFu - (unsigned)j);
          best = best > pk ? best : pk;
        }
      }
#pragma unroll
      for (int off = 32; off >= 1; off >>= 1) {
        unsigned long long o = __shfl_xor(best, off, 64);
        best = best > o ? best : o;
      }
      if (lane == 0) wred[p*16 + wid] = best;
      __syncthreads();
      if (wid == 0) {
        if (lane == 0) winLDS[1-p] = -1;   // safe: all waves past prev spin
        unsigned long long m = wred[p*16 + (lane & 15)];
#pragma unroll
        for (int off = 8; off >= 1; off >>= 1) {
          unsigned long long o = __shfl_xor(m, off, 64);
          m = m > o ? m : o;
        }
        if (lane == 0)
          __hip_atomic_store(&slot[it*FPSB + b], m,
                             __ATOMIC_RELAXED, __HIP_MEMORY_SCOPE_AGENT);
        unsigned long long v = 0ull;
        if (lane < FPSB) {
          const unsigned long long* sp = &slot[it*FPSB + lane];
          v = __hip_atomic_load(sp, __ATOMIC_RELAXED, __HIP_MEMORY_SCOPE_AGENT);
          while (v == 0ull)
            v = __hip_atomic_load(sp, __ATOMIC_RELAXED, __HIP_MEMORY_SCOPE_AGENT);
        }
#pragma unroll
        for (int off = 8; off >= 1; off >>= 1) {
          unsigned long long o = __shfl_xor(v, off, 64);
          v = v > o ? v : o;
        }
        v = __shfl(v, 0, 64);
        int win = (int)(0xFFFFFFFFu - (unsigned)(v & 0xFFFFFFFFull));
        if (lane == 0) {
          if (b == 0)
            __hip_atomic_store((unsigned*)&sampled[it+1], (unsigned)win,
                               __ATOMIC_RELAXED, __HIP_MEMORY_SCOPE_AGENT);
          winLDS[p] = win;
        }
        last = win;
      } else {
        int w = winLDS[p];
        while (w == -1) { __builtin_amdgcn_s_sleep(1); w = winLDS[p]; }
        last = w;
      }
    }
  } else {
    // ------------------ worker role: group + bn1 stats ------------------
    unsigned* hist  = (unsigned*)smraw;              // 8192
    unsigned* scan  = (unsigned*)(smraw + 32768);    // 1024
    unsigned* candK = (unsigned*)(smraw + 36864);    // 512
    int*      candI = (int*)(smraw + 38912);         // 512
    float*    feat  = (float*)(smraw + 40960);       // 768
    float*    cf    = (float*)(smraw + 44032);       // 8
    unsigned* ctl   = (unsigned*)(smraw + 44064);    // outcnt, candcnt
    volatile int* binfo = (volatile int*)(smraw + 44080); // B, bef, sid
    const int wkr = blockIdx.x - FPSB;               // 0..239
    for (int s = wkr; s < NSAMP; s += MEGA_BLOCKS - FPSB) {
      if (t == 0) {
        unsigned v = __hip_atomic_load((const unsigned*)&sampled[s],
                        __ATOMIC_RELAXED, __HIP_MEMORY_SCOPE_AGENT);
        while (v == 0xFFFFFFFFu) {
          __builtin_amdgcn_s_sleep(64);
          v = __hip_atomic_load((const unsigned*)&sampled[s],
                  __ATOMIC_RELAXED, __HIP_MEMORY_SCOPE_AGENT);
        }
        binfo[2] = (int)v;
        ctl[0] = 0u; ctl[1] = 0u;
      }
      for (int k = t; k < 8192; k += 1024) hist[k] = 0u;
      __syncthreads();
      const int sid = binfo[2];
      float4 c4 = xyzw[sid];
      const float cx=c4.x, cy=c4.y, cz=c4.z, c2=c4.w;
      for (int i = 0; i < N_PTS/1024; ++i) {
        int j = i*1024 + t;
        float4 p = xyzw[j];
        float dot = __fadd_rn(__fadd_rn(__fmul_rn(cx,p.x),__fmul_rn(cy,p.y)),__fmul_rn(cz,p.z));
        float d = __fsub_rn(__fadd_rn(c2, p.w), __fmul_rn(2.0f, dot));
        unsigned kb = __float_as_uint(d);
        kb ^= ((unsigned)((int)kb >> 31)) | 0x80000000u;
        atomicAdd(&hist[kb >> 19], 1u);
      }
      __syncthreads();
      unsigned ch = 0u;
      for (int k = 0; k < 8; ++k) ch += hist[t*8 + k];
      scan[t] = ch;
      __syncthreads();
      for (int off = 1; off < 1024; off <<= 1) {
        unsigned vv = (t >= off) ? scan[t - off] : 0u;
        __syncthreads();
        scan[t] += vv;
        __syncthreads();
      }
      unsigned inc = scan[t], before = inc - ch;
      if (before < NGRP && inc >= NGRP) {
        unsigned c = before;
        for (int k = 0; k < 8; ++k) {
          unsigned nb = hist[t*8 + k];
          if (c + nb >= NGRP) { binfo[0] = t*8 + k; binfo[1] = (int)c; break; }
          c += nb;
        }
      }
      __syncthreads();
      const unsigned B = (unsigned)binfo[0];
      const int bef = binfo[1];
      for (int i = 0; i < N_PTS/1024; ++i) {
        int j = i*1024 + t;
        float4 p = xyzw[j];
        float dot = __fadd_rn(__fadd_rn(__fmul_rn(cx,p.x),__fmul_rn(cy,p.y)),__fmul_rn(cz,p.z));
        float d = __fsub_rn(__fadd_rn(c2, p.w), __fmul_rn(2.0f, dot));
        unsigned kb = __float_as_uint(d);
        kb ^= ((unsigned)((int)kb >> 31)) | 0x80000000u;
        unsigned bin = kb >> 19;
        if (bin < B) {
          unsigned pos = atomicAdd(&ctl[0], 1u);
          groups[s*NGRP + pos] = j;
        } else if (bin == B) {
          unsigned ci = atomicAdd(&ctl[1], 1u);
          if (ci < GB_CAND) { candK[ci] = kb; candI[ci] = j; }
        }
      }
      __syncthreads();
      int M = ctl[1] < GB_CAND ? (int)ctl[1] : GB_CAND;
      int need = NGRP - bef;
      for (int c = t; c < M; c += 1024) {
        unsigned mk = candK[c]; int mi = candI[c];
        int rank = 0;
        for (int q = 0; q < M; ++q) {
          unsigned qk = candK[q];
          rank += (qk < mk || (qk == mk && candI[q] < mi)) ? 1 : 0;
        }
        if (rank < need) {
          unsigned pos = atomicAdd(&ctl[0], 1u);
          groups[s*NGRP + pos] = candI[c];
        }
      }
      __syncthreads();
      if (t == 0) {
        while (ctl[0] < NGRP) { groups[s*NGRP + ctl[0]] = 0; ctl[0]++; }
      }
      __syncthreads();
      if (t < DIMS) cf[t] = pts[sid*6 + t];
      __syncthreads();
      if (t < NGRP) {
        int g = groups[s*NGRP + t];
#pragma unroll
        for (int k = 0; k < DIMS; ++k) {
          float v = pts[g*6 + k];
          feat[t*12 + k] = v - cf[k];
          feat[t*12 + 6 + k] = v;
        }
      }
      __syncthreads();
      if (t < EMB) {
        float w[12];
#pragma unroll
        for (int k = 0; k < 12; ++k) w[k] = W1[k*EMB + t];
        float b = b1[t];
        float sum = 0.f, ss = 0.f;
        for (int r = 0; r < NGRP; ++r) {
          float y = b;
#pragma unroll
          for (int k = 0; k < 12; ++k) y += feat[r*12+k] * w[k];
          sum += y; ss += y*y;
        }
        atomicAdd(&gsum[t], sum);
        atomicAdd(&gss[t], ss);
      }
      __syncthreads();   // smraw reused next s
    }
  }
}

// ---------------- bn1 finalize ----------------------------------------------
__global__ __launch_bounds__(EMB) void k_finalize(const float* __restrict__ gsum,
    const float* __restrict__ gss, const float* __restrict__ scale,
    const float* __restrict__ bias, float* __restrict__ ac) {
  int c = threadIdx.x;
  float inv = 1.f / (float)ROWS;
  float mean = gsum[c] * inv;
  float var = gss[c] * inv - mean*mean;
  var = var < 0.f ? 0.f : var;
  float a = scale[c] * rsqrtf(var + EPS_BN);
  ac[c] = a; ac[EMB + c] = bias[c] - mean * a;
}

// ---------------- bn2 finalize from 32-sliced stats -------------------------
__global__ __launch_bounds__(EMB) void k_finalize2(const float* __restrict__ st2,
    const float* __restrict__ scale, const float* __restrict__ bias,
    float* __restrict__ ac) {
  int c = threadIdx.x;
  float sum = 0.f, ss = 0.f;
  for (int i = 0; i < 32; ++i) {
    sum += st2[i*1024 + c];
    ss  += st2[i*1024 + 512 + c];
  }
  float inv = 1.f / (float)ROWS;
  float mean = sum * inv;
  float var = ss * inv - mean*mean;
  var = var < 0.f ? 0.f : var;
  float a = scale[c] * rsqrtf(var + EPS_BN);
  ac[c] = a; ac[EMB + c] = bias[c] - mean * a;
}

// ---------------- fused MLP: fp32 GEMM1 -> bf16 MFMA GEMM2 ------------------
// 512 thr (8 waves). Wave w owns cols [64w,64w+64) = 4 col-tiles of 16.
// A (h1, 64x512 bf16, LDS stride 520): lane holds A[m=lane&15][k=quad*8+j].
// B (W2T[c][k] bf16 global): lane holds B[k=quad*8+j][n=lane&15] via one 16B load.
// C: col=lane&15 (verified m89); row mapping pooling-invariant.
__global__ __launch_bounds__(512, 4) void k_mlp(const float* __restrict__ pts,
    const int* __restrict__ sampled, const int* __restrict__ groups,
    const float* __restrict__ W1, const float* __restrict__ b1,
    const float* __restrict__ ac1, const unsigned short* __restrict__ W2T,
    const float* __restrict__ b2, const float* __restrict__ scale2,
    float* __restrict__ st2, float* __restrict__ y2sel) {
  const int s = blockIdx.x, t = threadIdx.x;
  extern __shared__ __align__(16) char smc[];
  float* feat = (float*)smc;                       // 768 f
  float* cf   = (float*)(smc + 3072);              // 8 f
  unsigned short* h1b = (unsigned short*)(smc + 3104);  // 64 x 520 bf16
  if (t < DIMS) cf[t] = pts[sampled[s]*6 + t];
  __syncthreads();
  if (t < NGRP) {
    int g = groups[s*NGRP + t];
#pragma unroll
    for (int k = 0; k < DIMS; ++k) {
      float v = pts[g*6 + k];
      feat[t*12+k]   = v - cf[k];
      feat[t*12+6+k] = v;
    }
  }
  __syncthreads();
  {  // GEMM1 + bn1 + relu, fp32; thread t = channel t over 64 rows
    float w[12];
#pragma unroll
    for (int k = 0; k < 12; ++k) w[k] = W1[k*EMB + t];
    float b = b1[t], a1 = ac1[t], c1 = ac1[EMB + t];
    for (int r = 0; r < NGRP; ++r) {
      float y = b;
#pragma unroll
      for (int k = 0; k < 12; ++k) y += feat[r*12+k] * w[k];
      float hv = a1*y + c1;
      h1b[r*H1B_S + t] = f2bf(hv > 0.f ? hv : 0.f);
    }
  }
  __syncthreads();
  const int lane = t & 63, w = t >> 6;
  const int quad = lane >> 4, l16 = lane & 15;
  float4v acc[4][4];   // [nt][mt]
#pragma unroll
  for (int nt = 0; nt < 4; ++nt) {
    float bv = b2[(w*4+nt)*16 + l16];
#pragma unroll
    for (int mt = 0; mt < 4; ++mt)
      acc[nt][mt] = (float4v){bv, bv, bv, bv};
  }
  for (int kc = 0; kc < 16; ++kc) {
    const int kb = kc*32 + quad*8;
    short8 af[4];
#pragma unroll
    for (int mt = 0; mt < 4; ++mt)
      af[mt] = *(const short8*)&h1b[(mt*16 + l16)*H1B_S + kb];
#pragma unroll
    for (int nt = 0; nt < 4; ++nt) {
      const int c = (w*4+nt)*16 + l16;
      short8 bf = *(const short8*)&W2T[c*EMB + kb];
#pragma unroll
      for (int mt = 0; mt < 4; ++mt)
        acc[nt][mt] = __builtin_amdgcn_mfma_f32_16x16x32_bf16(af[mt], bf, acc[nt][mt], 0, 0, 0);
    }
  }
  // epilogue: pool over rows per column; reduce across quad axis (bits 4,5)
#pragma unroll
  for (int nt = 0; nt < 4; ++nt) {
    float sm_ = 0.f, ss_ = 0.f, mx = -__builtin_inff(), mn = __builtin_inff();
#pragma unroll
    for (int mt = 0; mt < 4; ++mt)
#pragma unroll
      for (int i = 0; i < 4; ++i) {
        float v = acc[nt][mt][i];
        sm_ += v; ss_ += v*v;
        mx = fmaxf(mx, v); mn = fminf(mn, v);
      }
#pragma unroll
    for (int off = 16; off <= 32; off <<= 1) {
      sm_ += __shfl_xor(sm_, off, 64);
      ss_ += __shfl_xor(ss_, off, 64);
      mx = fmaxf(mx, __shfl_xor(mx, off, 64));
      mn = fminf(mn, __shfl_xor(mn, off, 64));
    }
    if (quad == 0) {
      int c = (w*4+nt)*16 + l16;
      atomicAdd(&st2[(s & 31)*1024 + c], sm_);
      atomicAdd(&st2[(s & 31)*1024 + 512 + c], ss_);
      y2sel[s*EMB + c] = (scale2[c] >= 0.f) ? mx : mn;
    }
  }
}

// ---------------- epilogue: bn2+relu on pooled extremum ---------------------
__global__ __launch_bounds__(256) void k_out(const float* __restrict__ y2sel,
    const float* __restrict__ ac2, float* __restrict__ out) {
  int i = blockIdx.x*256 + threadIdx.x;
  int c = i & (EMB-1);
  float a = ac2[c], cc = ac2[EMB + c];
  float v = a*y2sel[i] + cc;
  out[i] = v > 0.f ? v : 0.f;
}

extern "C" void kernel_launch(void* const* d_in, const int* in_sizes, int n_in,
                              void* d_out, int out_size, void* d_ws, size_t ws_size,
                              hipStream_t stream) {
  const float* pts    = (const float*)d_in[0];
  const float* W1     = (const float*)d_in[1];
  const float* b1     = (const float*)d_in[2];
  const float* scale1 = (const float*)d_in[3];
  const float* bias1  = (const float*)d_in[4];
  const float* W2     = (const float*)d_in[5];
  const float* b2     = (const float*)d_in[6];
  const float* scale2 = (const float*)d_in[7];
  const float* bias2  = (const float*)d_in[8];
  const int*   seed   = (const int*)d_in[9];
  float* out = (float*)d_out;

  char* ws = (char*)d_ws;
  int*    sampled = (int*)(ws);
  int*    groups  = (int*)(ws + 8192);
  float4* xyzw    = (float4*)(ws + 532480);
  float*  stats   = (float*)(ws + 1581056);          // gsum1/gss1 (bn1)
  float* gsum1 = stats, *gss1 = stats + 512;
  float*  ac1     = (float*)(ws + 1589248);
  float*  ac2     = (float*)(ws + 1593344);
  float*  y2sel   = (float*)(ws + 1597440);          // 4 MB
  // slot aliases y2sel (disjoint lifetime): 2047*16 u64 = 262KB < 4MB region
  unsigned long long* slot = (unsigned long long*)(ws + 1597440);
  unsigned short* W2T = (unsigned short*)(ws + 5791744);   // 512 KB bf16
  float* st2      = (float*)(ws + 6316032);          // 32 x 1024 sliced bn2 stats

  k_init<<<256, 256, 0, stream>>>(pts, W2, seed, slot, stats, st2, W2T, xyzw, sampled);
  k_mega<<<MEGA_BLOCKS, 1024, 0, stream>>>(xyzw, pts, W1, b1, slot, sampled,
                                           groups, gsum1, gss1);
  k_finalize<<<1, EMB, 0, stream>>>(gsum1, gss1, scale1, bias1, ac1);
  size_t mlp_lds = 3104 + (size_t)NGRP * H1B_S * sizeof(unsigned short);  // ~68 KB
  k_mlp<<<NSAMP, 512, mlp_lds, stream>>>(pts, sampled, groups, W1, b1, ac1,
                                         W2T, b2, scale2, st2, y2sel);
  k_finalize2<<<1, EMB, 0, stream>>>(st2, scale2, bias2, ac2);
  k_out<<<(out_size+255)/256, 256, 0, stream>>>(y2sel, ac2, out);
}

// Round 10
// 5162.730 us; speedup vs baseline: 1.4856x; 1.0070x over previous
//
#include <hip/hip_runtime.h>
#include <stdint.h>

#define N_PTS 65536
#define DIMS 6
#define NSAMP 2048
#define NGRP 64
#define EMB 512
#define ROWS (NSAMP*NGRP)
#define EPS_BN 1e-5f

#define FIRST_MODE 0

typedef __attribute__((ext_vector_type(8))) short short8;
typedef __attribute__((ext_vector_type(4))) float float4v;

__device__ __forceinline__ unsigned short f2bf(float f) {
  unsigned u = __float_as_uint(f);
  u += 0x7FFFu + ((u >> 16) & 1u);   // RNE
  return (unsigned short)(u >> 16);
}

// ---------------- Threefry-2x32, 20 rounds (JAX-compatible) ----------------
__device__ __forceinline__ void tf2x32(unsigned k0, unsigned k1, unsigned &x0, unsigned &x1) {
  unsigned ks[3] = {k0, k1, k0 ^ k1 ^ 0x1BD11BDAu};
  const unsigned R[8] = {13,15,26,6,17,29,16,24};
  x0 += ks[0]; x1 += ks[1];
#pragma unroll
  for (int g = 0; g < 5; ++g) {
#pragma unroll
    for (int j = 0; j < 4; ++j) {
      unsigned r = R[(g & 1) * 4 + j];
      x0 += x1;
      x1 = (x1 << r) | (x1 >> (32 - r));
      x1 ^= x0;
    }
    x0 += ks[(g + 1) % 3];
    x1 += ks[(g + 2) % 3] + (unsigned)(g + 1);
  }
}

__device__ __forceinline__ int compute_first(unsigned seed) {
  unsigned k0 = 0u, k1 = seed;
  unsigned s0, s1;
#if (FIRST_MODE == 0) || (FIRST_MODE == 1)
  { unsigned a0 = 0u, a1 = 1u; tf2x32(k0, k1, a0, a1); s0 = a0; s1 = a1; }
#else
  { unsigned p0 = 0u, p1 = 2u; tf2x32(k0, k1, p0, p1);
    unsigned q0 = 1u, q1 = 3u; tf2x32(k0, k1, q0, q1);
    s0 = p1; s1 = q1; }
#endif
  unsigned b0 = 0u, b1v = 0u; tf2x32(s0, s1, b0, b1v);
#if (FIRST_MODE == 0) || (FIRST_MODE == 3)
  unsigned bits = b0 ^ b1v;
#else
  unsigned bits = b0;
#endif
  return (int)(bits & 0xFFFFu);
}

// ---------------- geometry ---------------------------------------------------
#define FPSB 16                      // FPS blocks (16 slots = two 64B lines/iter)
#define MEGA_BLOCKS 256              // 16 FPS + 240 workers; 1 block/CU (LDS-forced)
#define FPS_PPT 4                    // 65536 / (16*1024)
#define GB_CAND 512
#define H1B_S 520                    // bf16 h1 LDS row stride (bank-benign)
#define MEGA_LDS 90112               // > 80 KB -> hardware cannot co-schedule 2 blocks/CU

// ---------------- init: xyzw, slots, stats, W2T(bf16), first idx ------------
__global__ __launch_bounds__(256) void k_init(const float* __restrict__ pts,
    const float* __restrict__ W2, const int* __restrict__ seed_arr,
    unsigned long long* __restrict__ slot, float* __restrict__ stats,
    float* __restrict__ st2, unsigned short* __restrict__ W2T,
    float4* __restrict__ xyzw, int* __restrict__ sampled) {
  int tid = blockIdx.x * 256 + threadIdx.x;        // 65536 threads
  if (tid < N_PTS) {
    float x = pts[tid*6], y = pts[tid*6+1], z = pts[tid*6+2];
    float p2 = __fadd_rn(__fadd_rn(__fmul_rn(x,x), __fmul_rn(y,y)), __fmul_rn(z,z));
    xyzw[tid] = make_float4(x, y, z, p2);
  }
#pragma unroll
  for (int i = 0; i < 4; ++i) {      // W2T[c][k] = bf16(W2[k][c]); writes coalesced
    int e = tid + i*65536;
    int c = e >> 9, k = e & 511;
    W2T[e] = f2bf(W2[k*EMB + c]);
  }
  if (tid < (NSAMP-1)*FPSB) slot[tid] = 0ull;
  if (tid < 4*EMB) stats[tid] = 0.f;
  if (tid < 32*1024) st2[tid] = 0.f;               // sliced bn2 stats
  if (tid >= 1 && tid < NSAMP) sampled[tid] = -1;  // sentinel for workers
  if (tid == 0) sampled[0] = compute_first((unsigned)seed_arr[0]);
}

// ---------------- mega: FPS blocks + group/stats worker blocks ---------------
// 88 KB dynamic LDS forces exactly 1 block/CU: FPS blocks never share a CU's
// SIMDs with a worker block (removes issue-bandwidth theft + per-iter skew on
// the serial critical path).
// FPS inner loop: no last-point exclusion needed -- the centroid's own
// distance is 0, so selected points' pd collapses to 0 and can never win
// (all unselected pds > 0; no duplicate points). Winner sequence bit-identical
// to the reference's -inf masking.
__global__ __launch_bounds__(1024) void k_mega(
    const float4* __restrict__ xyzw, const float* __restrict__ pts,
    const float* __restrict__ W1, const float* __restrict__ b1,
    unsigned long long* __restrict__ slot, int* __restrict__ sampled,
    int* __restrict__ groups, float* __restrict__ gsum, float* __restrict__ gss) {
  extern __shared__ __align__(16) char smraw[];
  const int t = threadIdx.x;
  if (blockIdx.x < FPSB) {
    // ------------------ FPS role ------------------
    unsigned long long* wred = (unsigned long long*)smraw;       // [2][16]
    volatile int* winLDS = (volatile int*)(smraw + 256);         // [2]
    const int b = blockIdx.x;
    const int T = b*1024 + t;                                    // 0..16383
    const int lane = t & 63, wid = t >> 6;
    float px[FPS_PPT], py[FPS_PPT], pz[FPS_PPT], pd[FPS_PPT];
    unsigned long long nidx[FPS_PPT];
#pragma unroll
    for (int i = 0; i < FPS_PPT; ++i) {
      float4 p = xyzw[T + 16384*i];
      px[i] = p.x; py[i] = p.y; pz[i] = p.z; pd[i] = __builtin_inff();
      nidx[i] = (unsigned long long)(0xFFFFFFFFu - (unsigned)(T + 16384*i));
    }
    if (t == 0) { winLDS[0] = -1; winLDS[1] = -1; }
    int last = sampled[0];
    __syncthreads();
    for (int it = 0; it < NSAMP-1; ++it) {
      const int p = it & 1;
      float4 cc = xyzw[last];
      unsigned long long best = 1ull;
#pragma unroll
      for (int i = 0; i < FPS_PPT; ++i) {
        float dx = __fsub_rn(px[i], cc.x);
        float dy = __fsub_rn(py[i], cc.y);
        float dz = __fsub_rn(pz[i], cc.z);
        float d = __fadd_rn(__fadd_rn(__fmul_rn(dx,dx), __fmul_rn(dy,dy)), __fmul_rn(dz,dz));
        pd[i] = fminf(pd[i], d);
        unsigned long long pk = ((unsigned long long)__float_as_uint(pd[i]) << 32) | nidx[i];
        best = best > pk ? best : pk;
      }
#pragma unroll
      for (int off = 32; off >= 1; off >>= 1) {
        unsigned long long o = __shfl_xor(best, off, 64);
        best = best > o ? best : o;
      }
      if (lane == 0) wred[p*16 + wid] = best;
      __syncthreads();
      if (wid == 0) {
        if (lane == 0) winLDS[1-p] = -1;   // safe: all waves past prev spin
        unsigned long long m = wred[p*16 + (lane & 15)];
#pragma unroll
        for (int off = 8; off >= 1; off >>= 1) {
          unsigned long long o = __shfl_xor(m, off, 64);
          m = m > o ? m : o;
        }
        if (lane == 0)
          __hip_atomic_store(&slot[it*FPSB + b], m,
                             __ATOMIC_RELAXED, __HIP_MEMORY_SCOPE_AGENT);
        unsigned long long v = 0ull;
        if (lane < FPSB) {
          const unsigned long long* sp = &slot[it*FPSB + lane];
          v = __hip_atomic_load(sp, __ATOMIC_RELAXED, __HIP_MEMORY_SCOPE_AGENT);
          while (v == 0ull)
            v = __hip_atomic_load(sp, __ATOMIC_RELAXED, __HIP_MEMORY_SCOPE_AGENT);
        }
#pragma unroll
        for (int off = 8; off >= 1; off >>= 1) {
          unsigned long long o = __shfl_xor(v, off, 64);
          v = v > o ? v : o;
        }
        v = __shfl(v, 0, 64);
        int win = (int)(0xFFFFFFFFu - (unsigned)(v & 0xFFFFFFFFull));
        if (lane == 0) {
          if (b == 0)
            __hip_atomic_store((unsigned*)&sampled[it+1], (unsigned)win,
                               __ATOMIC_RELAXED, __HIP_MEMORY_SCOPE_AGENT);
          winLDS[p] = win;
        }
        last = win;
      } else {
        int w = winLDS[p];
        while (w == -1) { __builtin_amdgcn_s_sleep(1); w = winLDS[p]; }
        last = w;
      }
    }
  } else {
    // ------------------ worker role: group + bn1 stats ------------------
    unsigned* hist  = (unsigned*)smraw;              // 8192
    unsigned* scan  = (unsigned*)(smraw + 32768);    // 1024
    unsigned* candK = (unsigned*)(smraw + 36864);    // 512
    int*      candI = (int*)(smraw + 38912);         // 512
    float*    feat  = (float*)(smraw + 40960);       // 768
    float*    cf    = (float*)(smraw + 44032);       // 8
    unsigned* ctl   = (unsigned*)(smraw + 44064);    // outcnt, candcnt
    volatile int* binfo = (volatile int*)(smraw + 44080); // B, bef, sid
    const int wkr = blockIdx.x - FPSB;               // 0..239
    for (int s = wkr; s < NSAMP; s += MEGA_BLOCKS - FPSB) {
      if (t == 0) {
        unsigned v = __hip_atomic_load((const unsigned*)&sampled[s],
                        __ATOMIC_RELAXED, __HIP_MEMORY_SCOPE_AGENT);
        while (v == 0xFFFFFFFFu) {
          __builtin_amdgcn_s_sleep(64);
          v = __hip_atomic_load((const unsigned*)&sampled[s],
                  __ATOMIC_RELAXED, __HIP_MEMORY_SCOPE_AGENT);
        }
        binfo[2] = (int)v;
        ctl[0] = 0u; ctl[1] = 0u;
      }
      for (int k = t; k < 8192; k += 1024) hist[k] = 0u;
      __syncthreads();
      const int sid = binfo[2];
      float4 c4 = xyzw[sid];
      const float cx=c4.x, cy=c4.y, cz=c4.z, c2=c4.w;
      for (int i = 0; i < N_PTS/1024; ++i) {
        int j = i*1024 + t;
        float4 p = xyzw[j];
        float dot = __fadd_rn(__fadd_rn(__fmul_rn(cx,p.x),__fmul_rn(cy,p.y)),__fmul_rn(cz,p.z));
        float d = __fsub_rn(__fadd_rn(c2, p.w), __fmul_rn(2.0f, dot));
        unsigned kb = __float_as_uint(d);
        kb ^= ((unsigned)((int)kb >> 31)) | 0x80000000u;
        atomicAdd(&hist[kb >> 19], 1u);
      }
      __syncthreads();
      unsigned ch = 0u;
      for (int k = 0; k < 8; ++k) ch += hist[t*8 + k];
      scan[t] = ch;
      __syncthreads();
      for (int off = 1; off < 1024; off <<= 1) {
        unsigned vv = (t >= off) ? scan[t - off] : 0u;
        __syncthreads();
        scan[t] += vv;
        __syncthreads();
      }
      unsigned inc = scan[t], before = inc - ch;
      if (before < NGRP && inc >= NGRP) {
        unsigned c = before;
        for (int k = 0; k < 8; ++k) {
          unsigned nb = hist[t*8 + k];
          if (c + nb >= NGRP) { binfo[0] = t*8 + k; binfo[1] = (int)c; break; }
          c += nb;
        }
      }
      __syncthreads();
      const unsigned B = (unsigned)binfo[0];
      const int bef = binfo[1];
      for (int i = 0; i < N_PTS/1024; ++i) {
        int j = i*1024 + t;
        float4 p = xyzw[j];
        float dot = __fadd_rn(__fadd_rn(__fmul_rn(cx,p.x),__fmul_rn(cy,p.y)),__fmul_rn(cz,p.z));
        float d = __fsub_rn(__fadd_rn(c2, p.w), __fmul_rn(2.0f, dot));
        unsigned kb = __float_as_uint(d);
        kb ^= ((unsigned)((int)kb >> 31)) | 0x80000000u;
        unsigned bin = kb >> 19;
        if (bin < B) {
          unsigned pos = atomicAdd(&ctl[0], 1u);
          groups[s*NGRP + pos] = j;
        } else if (bin == B) {
          unsigned ci = atomicAdd(&ctl[1], 1u);
          if (ci < GB_CAND) { candK[ci] = kb; candI[ci] = j; }
        }
      }
      __syncthreads();
      int M = ctl[1] < GB_CAND ? (int)ctl[1] : GB_CAND;
      int need = NGRP - bef;
      for (int c = t; c < M; c += 1024) {
        unsigned mk = candK[c]; int mi = candI[c];
        int rank = 0;
        for (int q = 0; q < M; ++q) {
          unsigned qk = candK[q];
          rank += (qk < mk || (qk == mk && candI[q] < mi)) ? 1 : 0;
        }
        if (rank < need) {
          unsigned pos = atomicAdd(&ctl[0], 1u);
          groups[s*NGRP + pos] = candI[c];
        }
      }
      __syncthreads();
      if (t == 0) {
        while (ctl[0] < NGRP) { groups[s*NGRP + ctl[0]] = 0; ctl[0]++; }
      }
      __syncthreads();
      if (t < DIMS) cf[t] = pts[sid*6 + t];
      __syncthreads();
      if (t < NGRP) {
        int g = groups[s*NGRP + t];
#pragma unroll
        for (int k = 0; k < DIMS; ++k) {
          float v = pts[g*6 + k];
          feat[t*12 + k] = v - cf[k];
          feat[t*12 + 6 + k] = v;
        }
      }
      __syncthreads();
      if (t < EMB) {
        float w[12];
#pragma unroll
        for (int k = 0; k < 12; ++k) w[k] = W1[k*EMB + t];
        float b = b1[t];
        float sum = 0.f, ss = 0.f;
        for (int r = 0; r < NGRP; ++r) {
          float y = b;
#pragma unroll
          for (int k = 0; k < 12; ++k) y += feat[r*12+k] * w[k];
          sum += y; ss += y*y;
        }
        atomicAdd(&gsum[t], sum);
        atomicAdd(&gss[t], ss);
      }
      __syncthreads();   // smraw reused next s
    }
  }
}

// ---------------- bn1 finalize ----------------------------------------------
__global__ __launch_bounds__(EMB) void k_finalize(const float* __restrict__ gsum,
    const float* __restrict__ gss, const float* __restrict__ scale,
    const float* __restrict__ bias, float* __restrict__ ac) {
  int c = threadIdx.x;
  float inv = 1.f / (float)ROWS;
  float mean = gsum[c] * inv;
  float var = gss[c] * inv - mean*mean;
  var = var < 0.f ? 0.f : var;
  float a = scale[c] * rsqrtf(var + EPS_BN);
  ac[c] = a; ac[EMB + c] = bias[c] - mean * a;
}

// ---------------- bn2 finalize from 32-sliced stats -------------------------
__global__ __launch_bounds__(EMB) void k_finalize2(const float* __restrict__ st2,
    const float* __restrict__ scale, const float* __restrict__ bias,
    float* __restrict__ ac) {
  int c = threadIdx.x;
  float sum = 0.f, ss = 0.f;
  for (int i = 0; i < 32; ++i) {
    sum += st2[i*1024 + c];
    ss  += st2[i*1024 + 512 + c];
  }
  float inv = 1.f / (float)ROWS;
  float mean = sum * inv;
  float var = ss * inv - mean*mean;
  var = var < 0.f ? 0.f : var;
  float a = scale[c] * rsqrtf(var + EPS_BN);
  ac[c] = a; ac[EMB + c] = bias[c] - mean * a;
}

// ---------------- fused MLP: fp32 GEMM1 -> bf16 MFMA GEMM2 ------------------
__global__ __launch_bounds__(512, 4) void k_mlp(const float* __restrict__ pts,
    const int* __restrict__ sampled, const int* __restrict__ groups,
    const float* __restrict__ W1, const float* __restrict__ b1,
    const float* __restrict__ ac1, const unsigned short* __restrict__ W2T,
    const float* __restrict__ b2, const float* __restrict__ scale2,
    float* __restrict__ st2, float* __restrict__ y2sel) {
  const int s = blockIdx.x, t = threadIdx.x;
  extern __shared__ __align__(16) char smc[];
  float* feat = (float*)smc;                       // 768 f
  float* cf   = (float*)(smc + 3072);              // 8 f
  unsigned short* h1b = (unsigned short*)(smc + 3104);  // 64 x 520 bf16
  if (t < DIMS) cf[t] = pts[sampled[s]*6 + t];
  __syncthreads();
  if (t < NGRP) {
    int g = groups[s*NGRP + t];
#pragma unroll
    for (int k = 0; k < DIMS; ++k) {
      float v = pts[g*6 + k];
      feat[t*12+k]   = v - cf[k];
      feat[t*12+6+k] = v;
    }
  }
  __syncthreads();
  {  // GEMM1 + bn1 + relu, fp32; thread t = channel t over 64 rows
    float w[12];
#pragma unroll
    for (int k = 0; k < 12; ++k) w[k] = W1[k*EMB + t];
    float b = b1[t], a1 = ac1[t], c1 = ac1[EMB + t];
    for (int r = 0; r < NGRP; ++r) {
      float y = b;
#pragma unroll
      for (int k = 0; k < 12; ++k) y += feat[r*12+k] * w[k];
      float hv = a1*y + c1;
      h1b[r*H1B_S + t] = f2bf(hv > 0.f ? hv : 0.f);
    }
  }
  __syncthreads();
  const int lane = t & 63, w = t >> 6;
  const int quad = lane >> 4, l16 = lane & 15;
  float4v acc[4][4];   // [nt][mt]
#pragma unroll
  for (int nt = 0; nt < 4; ++nt) {
    float bv = b2[(w*4+nt)*16 + l16];
#pragma unroll
    for (int mt = 0; mt < 4; ++mt)
      acc[nt][mt] = (float4v){bv, bv, bv, bv};
  }
  for (int kc = 0; kc < 16; ++kc) {
    const int kb = kc*32 + quad*8;
    short8 af[4];
#pragma unroll
    for (int mt = 0; mt < 4; ++mt)
      af[mt] = *(const short8*)&h1b[(mt*16 + l16)*H1B_S + kb];
#pragma unroll
    for (int nt = 0; nt < 4; ++nt) {
      const int c = (w*4+nt)*16 + l16;
      short8 bf = *(const short8*)&W2T[c*EMB + kb];
#pragma unroll
      for (int mt = 0; mt < 4; ++mt)
        acc[nt][mt] = __builtin_amdgcn_mfma_f32_16x16x32_bf16(af[mt], bf, acc[nt][mt], 0, 0, 0);
    }
  }
#pragma unroll
  for (int nt = 0; nt < 4; ++nt) {
    float sm_ = 0.f, ss_ = 0.f, mx = -__builtin_inff(), mn = __builtin_inff();
#pragma unroll
    for (int mt = 0; mt < 4; ++mt)
#pragma unroll
      for (int i = 0; i < 4; ++i) {
        float v = acc[nt][mt][i];
        sm_ += v; ss_ += v*v;
        mx = fmaxf(mx, v); mn = fminf(mn, v);
      }
#pragma unroll
    for (int off = 16; off <= 32; off <<= 1) {
      sm_ += __shfl_xor(sm_, off, 64);
      ss_ += __shfl_xor(ss_, off, 64);
      mx = fmaxf(mx, __shfl_xor(mx, off, 64));
      mn = fminf(mn, __shfl_xor(mn, off, 64));
    }
    if (quad == 0) {
      int c = (w*4+nt)*16 + l16;
      atomicAdd(&st2[(s & 31)*1024 + c], sm_);
      atomicAdd(&st2[(s & 31)*1024 + 512 + c], ss_);
      y2sel[s*EMB + c] = (scale2[c] >= 0.f) ? mx : mn;
    }
  }
}

// ---------------- epilogue: bn2+relu on pooled extremum ---------------------
__global__ __launch_bounds__(256) void k_out(const float* __restrict__ y2sel,
    const float* __restrict__ ac2, float* __restrict__ out) {
  int i = blockIdx.x*256 + threadIdx.x;
  int c = i & (EMB-1);
  float a = ac2[c], cc = ac2[EMB + c];
  float v = a*y2sel[i] + cc;
  out[i] = v > 0.f ? v : 0.f;
}

extern "C" void kernel_launch(void* const* d_in, const int* in_sizes, int n_in,
                              void* d_out, int out_size, void* d_ws, size_t ws_size,
                              hipStream_t stream) {
  const float* pts    = (const float*)d_in[0];
  const float* W1     = (const float*)d_in[1];
  const float* b1     = (const float*)d_in[2];
  const float* scale1 = (const float*)d_in[3];
  const float* bias1  = (const float*)d_in[4];
  const float* W2     = (const float*)d_in[5];
  const float* b2     = (const float*)d_in[6];
  const float* scale2 = (const float*)d_in[7];
  const float* bias2  = (const float*)d_in[8];
  const int*   seed   = (const int*)d_in[9];
  float* out = (float*)d_out;

  char* ws = (char*)d_ws;
  int*    sampled = (int*)(ws);
  int*    groups  = (int*)(ws + 8192);
  float4* xyzw    = (float4*)(ws + 532480);
  float*  stats   = (float*)(ws + 1581056);          // gsum1/gss1 (bn1)
  float* gsum1 = stats, *gss1 = stats + 512;
  float*  ac1     = (float*)(ws + 1589248);
  float*  ac2     = (float*)(ws + 1593344);
  float*  y2sel   = (float*)(ws + 1597440);          // 4 MB
  // slot aliases y2sel (disjoint lifetime): 2047*16 u64 = 262KB < 4MB region
  unsigned long long* slot = (unsigned long long*)(ws + 1597440);
  unsigned short* W2T = (unsigned short*)(ws + 5791744);   // 512 KB bf16
  float* st2      = (float*)(ws + 6316032);          // 32 x 1024 sliced bn2 stats

  k_init<<<256, 256, 0, stream>>>(pts, W2, seed, slot, stats, st2, W2T, xyzw, sampled);
  k_mega<<<MEGA_BLOCKS, 1024, MEGA_LDS, stream>>>(xyzw, pts, W1, b1, slot, sampled,
                                                  groups, gsum1, gss1);
  k_finalize<<<1, EMB, 0, stream>>>(gsum1, gss1, scale1, bias1, ac1);
  size_t mlp_lds = 3104 + (size_t)NGRP * H1B_S * sizeof(unsigned short);  // ~68 KB
  k_mlp<<<NSAMP, 512, mlp_lds, stream>>>(pts, sampled, groups, W1, b1, ac1,
                                         W2T, b2, scale2, st2, y2sel);
  k_finalize2<<<1, EMB, 0, stream>>>(st2, scale2, bias2, ac2);
  k_out<<<(out_size+255)/256, 256, 0, stream>>>(y2sel, ac2, out);
}